// Round 4
// baseline (480.991 us; speedup 1.0000x reference)
//
#include <hip/hip_runtime.h>

// fastmax attention, barrier-free MFMA main loop. b=4,h=16,n=1024,d=64 fp32.
// Pre-kernels split k (normalized), v'=v+0.1*noise (transposed), rpe into
// bf16 hi/lo arrays in d_ws. Main kernel: each wave owns 16 q rows; all
// MFMA B-fragments load directly from ws (L2-hot); Bst/S transposes are
// intra-wave LDS round-trips fenced with s_waitcnt lgkmcnt(0) -- zero
// __syncthreads in the K-loop. bf16x3 split precision (hi*hi+hi*lo+lo*hi).

constexpr int N   = 1024;
constexpr int D   = 64;
constexpr int NBH = 64;
constexpr int BM  = 64;

// ws layout (bytes)
constexpr size_t KH_OFF = 0;                                  // k_hi [bh][row][t]
constexpr size_t KL_OFF = KH_OFF + (size_t)NBH * N * D * 2;
constexpr size_t VH_OFF = KL_OFF + (size_t)NBH * N * D * 2;   // vt_hi [bh][dc][c]
constexpr size_t VL_OFF = VH_OFF + (size_t)NBH * N * D * 2;
constexpr size_t RH_OFF = VL_OFF + (size_t)NBH * N * D * 2;   // r_hi [rel 2048][t]
constexpr size_t RL_OFF = RH_OFF + (size_t)2048 * D * 2;

typedef short short8  __attribute__((ext_vector_type(8)));
typedef float float4v __attribute__((ext_vector_type(4)));

#define LDS_FENCE() asm volatile("s_waitcnt lgkmcnt(0)" ::: "memory")

__device__ __forceinline__ ushort f2bf(float x) {
    union { float f; unsigned u; } un; un.f = x;
    unsigned r = un.u + 0x7fffu + ((un.u >> 16) & 1u);   // RNE
    return (ushort)(r >> 16);
}
__device__ __forceinline__ float bf2f(ushort h) {
    union { unsigned u; float f; } un; un.u = ((unsigned)h) << 16;
    return un.f;
}
__device__ __forceinline__ void split2(float x, ushort& h, ushort& l) {
    h = f2bf(x);
    l = f2bf(x - bf2f(h));
}
__device__ __forceinline__ void pack16(const float* v, ushort* dh, ushort* dl) {
    ushort hh[16], ll[16];
#pragma unroll
    for (int j = 0; j < 16; ++j) split2(v[j], hh[j], ll[j]);
    uint4 a, b;
    a.x = hh[0] | (hh[1] << 16);  a.y = hh[2] | (hh[3] << 16);
    a.z = hh[4] | (hh[5] << 16);  a.w = hh[6] | (hh[7] << 16);
    b.x = hh[8] | (hh[9] << 16);  b.y = hh[10] | (hh[11] << 16);
    b.z = hh[12] | (hh[13] << 16); b.w = hh[14] | (hh[15] << 16);
    ((uint4*)dh)[0] = a; ((uint4*)dh)[1] = b;
    a.x = ll[0] | (ll[1] << 16);  a.y = ll[2] | (ll[3] << 16);
    a.z = ll[4] | (ll[5] << 16);  a.w = ll[6] | (ll[7] << 16);
    b.x = ll[8] | (ll[9] << 16);  b.y = ll[10] | (ll[11] << 16);
    b.z = ll[12] | (ll[13] << 16); b.w = ll[14] | (ll[15] << 16);
    ((uint4*)dl)[0] = a; ((uint4*)dl)[1] = b;
}

// ---- pre-kernels ----
__global__ __launch_bounds__(256) void prep_k(const float* __restrict__ kg,
                                              ushort* __restrict__ kh,
                                              ushort* __restrict__ kl) {
    const int bh = blockIdx.y;
    const int row = blockIdx.x * 64 + (threadIdx.x >> 2);
    const int seg = threadIdx.x & 3;
    const float4* p = (const float4*)(kg + ((size_t)bh * N + row) * D + seg * 16);
    float4 f[4] = {p[0], p[1], p[2], p[3]};
    float ss = 0.f;
#pragma unroll
    for (int i = 0; i < 4; ++i)
        ss += f[i].x * f[i].x + f[i].y * f[i].y + f[i].z * f[i].z + f[i].w * f[i].w;
    ss += __shfl_xor(ss, 1, 4);
    ss += __shfl_xor(ss, 2, 4);
    const float rn = rsqrtf(ss);
    float v[16];
#pragma unroll
    for (int i = 0; i < 4; ++i) {
        v[4 * i + 0] = f[i].x * rn; v[4 * i + 1] = f[i].y * rn;
        v[4 * i + 2] = f[i].z * rn; v[4 * i + 3] = f[i].w * rn;
    }
    const size_t o = ((size_t)bh * N + row) * D + seg * 16;
    pack16(v, kh + o, kl + o);
}

__global__ __launch_bounds__(256) void prep_rpe(const float* __restrict__ rg,
                                                ushort* __restrict__ rh,
                                                ushort* __restrict__ rl) {
    const int row = blockIdx.x * 64 + (threadIdx.x >> 2);
    if (row >= 2 * N - 1) return;
    const int seg = threadIdx.x & 3;
    const float4* p = (const float4*)(rg + (size_t)row * D + seg * 16);
    float4 f[4] = {p[0], p[1], p[2], p[3]};
    float v[16];
#pragma unroll
    for (int i = 0; i < 4; ++i) {
        v[4 * i + 0] = f[i].x; v[4 * i + 1] = f[i].y;
        v[4 * i + 2] = f[i].z; v[4 * i + 3] = f[i].w;
    }
    const size_t o = (size_t)row * D + seg * 16;
    pack16(v, rh + o, rl + o);
}

__global__ __launch_bounds__(256) void prep_v(const float* __restrict__ vg,
                                              const float* __restrict__ ng,
                                              ushort* __restrict__ vh,
                                              ushort* __restrict__ vl) {
    __shared__ ushort Th[64 * 72], Tl[64 * 72];
    const int bh = blockIdx.y, c0 = blockIdx.x * 64;
    const int cl = threadIdx.x >> 2, seg = threadIdx.x & 3;
    {
        const float4* pv = (const float4*)(vg + ((size_t)bh * N + c0 + cl) * D + seg * 16);
        const float4* pn = (const float4*)(ng + ((size_t)bh * N + c0 + cl) * D + seg * 16);
#pragma unroll
        for (int i = 0; i < 4; ++i) {
            float4 fv = pv[i], fn = pn[i];
            float va[4] = {fv.x + 0.1f * fn.x, fv.y + 0.1f * fn.y,
                           fv.z + 0.1f * fn.z, fv.w + 0.1f * fn.w};
#pragma unroll
            for (int j = 0; j < 4; ++j) {
                ushort hh, ll;
                split2(va[j], hh, ll);
                const int dc = seg * 16 + i * 4 + j;
                Th[dc * 72 + cl] = hh;
                Tl[dc * 72 + cl] = ll;
            }
        }
    }
    __syncthreads();
    {
        const int dc = threadIdx.x >> 2;
        const size_t o = ((size_t)bh * D + dc) * N + c0 + seg * 16;
        uint4* sh = (uint4*)&Th[dc * 72 + seg * 16];
        uint4* sl = (uint4*)&Tl[dc * 72 + seg * 16];
        ((uint4*)(vh + o))[0] = sh[0]; ((uint4*)(vh + o))[1] = sh[1];
        ((uint4*)(vl + o))[0] = sl[0]; ((uint4*)(vl + o))[1] = sl[1];
    }
}

// ---- main ----
__device__ __forceinline__ float4v mfma6(short8 ah0, short8 ah1, short8 al0, short8 al1,
                                         const ushort* ph, const ushort* pl, float4v c) {
    short8 bh0 = *(const short8*)ph;
    short8 bh1 = *(const short8*)(ph + 32);
    short8 bl0 = *(const short8*)pl;
    short8 bl1 = *(const short8*)(pl + 32);
    c = __builtin_amdgcn_mfma_f32_16x16x32_bf16(ah0, bh0, c, 0, 0, 0);
    c = __builtin_amdgcn_mfma_f32_16x16x32_bf16(ah1, bh1, c, 0, 0, 0);
    c = __builtin_amdgcn_mfma_f32_16x16x32_bf16(ah0, bl0, c, 0, 0, 0);
    c = __builtin_amdgcn_mfma_f32_16x16x32_bf16(ah1, bl1, c, 0, 0, 0);
    c = __builtin_amdgcn_mfma_f32_16x16x32_bf16(al0, bh0, c, 0, 0, 0);
    c = __builtin_amdgcn_mfma_f32_16x16x32_bf16(al1, bh1, c, 0, 0, 0);
    return c;
}

__global__ __launch_bounds__(256, 4)
void fastmax_main(const float* __restrict__ qg,
                  const ushort* __restrict__ kh, const ushort* __restrict__ kl,
                  const ushort* __restrict__ vh, const ushort* __restrict__ vl,
                  const ushort* __restrict__ rh, const ushort* __restrict__ rl,
                  float* __restrict__ og) {
    __shared__ char scratch[4 * 5760];   // per-wave: Bst[80][18] f32  OR  S hi/lo [16][72] bf16
    const int tid  = threadIdx.x;
    const int lane = tid & 63;
    const int wv   = tid >> 6;
    const int bh   = blockIdx.y;
    const int bix  = gridDim.x - 1 - blockIdx.x;   // heaviest (largest bix) dispatch first
    const int i0   = bix * BM;
    const int x    = lane & 15;
    const int quad = lane >> 4;
    const int band = wv * 16;

    float*  Bst = (float*)(scratch + wv * 5760);
    ushort* Sh  = (ushort*)(scratch + wv * 5760);
    ushort* Sl  = Sh + 16 * 72;

    // ---- load + normalize + split this wave's 16 q rows (A-frags) ----
    const float* qrow = qg + ((size_t)bh * N + i0 + band + x) * D;
    float qf[16];
    *(float4*)&qf[0]  = *(const float4*)(qrow + quad * 8);
    *(float4*)&qf[4]  = *(const float4*)(qrow + quad * 8 + 4);
    *(float4*)&qf[8]  = *(const float4*)(qrow + 32 + quad * 8);
    *(float4*)&qf[12] = *(const float4*)(qrow + 32 + quad * 8 + 4);
    float ss = 0.f;
#pragma unroll
    for (int j = 0; j < 16; ++j) ss += qf[j] * qf[j];
    ss += __shfl_xor(ss, 16);
    ss += __shfl_xor(ss, 32);
    const float rn = rsqrtf(ss);
    short8 qh0, ql0, qh1, ql1;
#pragma unroll
    for (int j = 0; j < 8; ++j) {
        ushort h, l;
        split2(qf[j] * rn, h, l);      qh0[j] = (short)h; ql0[j] = (short)l;
        split2(qf[8 + j] * rn, h, l);  qh1[j] = (short)h; ql1[j] = (short)l;
    }

    float4v oacc[4];
#pragma unroll
    for (int i = 0; i < 4; ++i) oacc[i] = (float4v){0.f, 0.f, 0.f, 0.f};
    float pden[4] = {0.f, 0.f, 0.f, 0.f};

    const ushort* khb = kh + (size_t)bh * N * D;
    const ushort* klb = kl + (size_t)bh * N * D;
    const ushort* vhb = vh + (size_t)bh * D * N;
    const ushort* vlb = vl + (size_t)bh * D * N;

    for (int jt = 0; jt <= bix; ++jt) {
        const int j0   = jt * BM;
        const int rel0 = i0 - j0 + N - 64;

        // ---- QK^T: S frags ----
        float4v sacc[4];
#pragma unroll
        for (int nt = 0; nt < 4; ++nt) {
            const size_t o = (size_t)(j0 + nt * 16 + x) * D + quad * 8;
            float4v c = (float4v){0.f, 0.f, 0.f, 0.f};
            sacc[nt] = mfma6(qh0, qh1, ql0, ql1, khb + o, klb + o, c);
        }
        // ---- QR: only the 5 w-tiles this wave gathers from (w in [band, band+80)) ----
        float4v racc[5];
#pragma unroll
        for (int t = 0; t < 5; ++t) {
            const size_t o = (size_t)(rel0 + band + t * 16 + x) * D + quad * 8;
            float4v c = (float4v){0.f, 0.f, 0.f, 0.f};
            racc[t] = mfma6(qh0, qh1, ql0, ql1, rh + o, rl + o, c);
        }

        // ---- intra-wave Bst transpose (w_loc = w - band) ----
#pragma unroll
        for (int t = 0; t < 5; ++t) {
            float* p = &Bst[(t * 16 + x) * 18 + quad * 4];
            float2 a; a.x = racc[t][0]; a.y = racc[t][1];
            float2 b; b.x = racc[t][2]; b.y = racc[t][3];
            *(float2*)p = a;
            *(float2*)(p + 2) = b;
        }
        LDS_FENCE();

        // ---- gather bias, assemble S, denom ----
        const bool diag = (jt == bix);
        float s[4][4];
#pragma unroll
        for (int nt = 0; nt < 4; ++nt) {
#pragma unroll
            for (int rr = 0; rr < 4; ++rr) {
                const int rt = band + quad * 4 + rr;      // row in tile
                const int ct = nt * 16 + x;               // col in tile
                const int wl = rt - ct + 63 - band;       // in [0, 79]
                float val = sacc[nt][rr] + Bst[wl * 18 + quad * 4 + rr] + 1.0f;
                if (diag && ct > rt) val = 0.f;
                pden[rr] += val;
                s[nt][rr] = val;
            }
        }
        LDS_FENCE();

        // ---- intra-wave S store (hi/lo) + A-frag reload ----
#pragma unroll
        for (int nt = 0; nt < 4; ++nt)
#pragma unroll
            for (int rr = 0; rr < 4; ++rr) {
                ushort hh, ll;
                split2(s[nt][rr], hh, ll);
                Sh[(quad * 4 + rr) * 72 + nt * 16 + x] = hh;
                Sl[(quad * 4 + rr) * 72 + nt * 16 + x] = ll;
            }
        LDS_FENCE();
        const short8 sh0 = *(const short8*)&Sh[x * 72 + quad * 8];
        const short8 sh1 = *(const short8*)&Sh[x * 72 + 32 + quad * 8];
        const short8 sl0 = *(const short8*)&Sl[x * 72 + quad * 8];
        const short8 sl1 = *(const short8*)&Sl[x * 72 + 32 + quad * 8];

        // ---- O += S @ V' ----
#pragma unroll
        for (int nt = 0; nt < 4; ++nt) {
            const size_t o = (size_t)(nt * 16 + x) * N + j0 + quad * 8;
            oacc[nt] = mfma6(sh0, sh1, sl0, sl1, vhb + o, vlb + o, oacc[nt]);
        }
        LDS_FENCE();   // Bst writes of next iter must not pass S reads
    }

    // ---- denominators (reduce over 16 lanes of this quad-group) + store ----
    float inv[4];
#pragma unroll
    for (int rr = 0; rr < 4; ++rr) {
        float d = pden[rr];
        d += __shfl_xor(d, 1, 16);
        d += __shfl_xor(d, 2, 16);
        d += __shfl_xor(d, 4, 16);
        d += __shfl_xor(d, 8, 16);
        inv[rr] = 1.0f / d;
    }
    float* outp = og + ((size_t)bh * N + i0 + band) * D;
#pragma unroll
    for (int nt = 0; nt < 4; ++nt)
#pragma unroll
        for (int rr = 0; rr < 4; ++rr)
            outp[(size_t)(quad * 4 + rr) * D + nt * 16 + x] = oacc[nt][rr] * inv[rr];
}

extern "C" void kernel_launch(void* const* d_in, const int* in_sizes, int n_in,
                              void* d_out, int out_size, void* d_ws, size_t ws_size,
                              hipStream_t stream) {
    const float* q   = (const float*)d_in[0];
    const float* k   = (const float*)d_in[1];
    const float* v   = (const float*)d_in[2];
    const float* dn  = (const float*)d_in[3];
    const float* rpe = (const float*)d_in[4];
    float* out = (float*)d_out;
    char* ws = (char*)d_ws;

    ushort* kh = (ushort*)(ws + KH_OFF);
    ushort* kl = (ushort*)(ws + KL_OFF);
    ushort* vh = (ushort*)(ws + VH_OFF);
    ushort* vl = (ushort*)(ws + VL_OFF);
    ushort* rh = (ushort*)(ws + RH_OFF);
    ushort* rl = (ushort*)(ws + RL_OFF);

    prep_k  <<<dim3(N / 64, NBH), 256, 0, stream>>>(k, kh, kl);
    prep_v  <<<dim3(N / 64, NBH), 256, 0, stream>>>(v, dn, vh, vl);
    prep_rpe<<<dim3(32), 256, 0, stream>>>(rpe, rh, rl);
    fastmax_main<<<dim3(N / BM, NBH), 256, 0, stream>>>(q, kh, kl, vh, vl, rh, rl, out);
}

// Round 5
// 196.692 us; speedup vs baseline: 2.4454x; 2.4454x over previous
//
#include <hip/hip_runtime.h>

// fastmax attention. b=4,h=16,n=1024,d=64 fp32. bf16x3 split precision.
// Prep kernels: split k (l2-normalized), v'=v+0.1*noise (transposed), rpe
// into bf16 hi/lo arrays in d_ws (once per element).
// Main kernel: LDS-staged tiles (pure b128 copies), per-wave QR (5 w-tiles),
// per-wave LDS scratch for Bst/S transposes (lgkmcnt fences, no barrier),
// 3 __syncthreads per K-iter. Each block does q-tiles {bix, 15-bix} -> all
// 512 blocks do exactly 17 iters (2 blocks/CU, fully resident, no tail).

constexpr int N   = 1024;
constexpr int D   = 64;
constexpr int NBH = 64;
constexpr int LDT = 72;   // ushort stride of staged tiles

// ws layout (bytes)
constexpr size_t KH_OFF = 0;                                  // k_hi [bh][row][t]
constexpr size_t KL_OFF = KH_OFF + (size_t)NBH * N * D * 2;
constexpr size_t VH_OFF = KL_OFF + (size_t)NBH * N * D * 2;   // vt_hi [bh][dc][c]
constexpr size_t VL_OFF = VH_OFF + (size_t)NBH * N * D * 2;
constexpr size_t RH_OFF = VL_OFF + (size_t)NBH * N * D * 2;   // r_hi [rel 2048][t]
constexpr size_t RL_OFF = RH_OFF + (size_t)2048 * D * 2;

typedef short short8  __attribute__((ext_vector_type(8)));
typedef float float4v __attribute__((ext_vector_type(4)));

#define LDS_FENCE() asm volatile("s_waitcnt lgkmcnt(0)" ::: "memory")

__device__ __forceinline__ ushort f2bf(float x) {
    union { float f; unsigned u; } un; un.f = x;
    unsigned r = un.u + 0x7fffu + ((un.u >> 16) & 1u);   // RNE
    return (ushort)(r >> 16);
}
__device__ __forceinline__ float bf2f(ushort h) {
    union { unsigned u; float f; } un; un.u = ((unsigned)h) << 16;
    return un.f;
}
__device__ __forceinline__ void split2(float x, ushort& h, ushort& l) {
    h = f2bf(x);
    l = f2bf(x - bf2f(h));
}
__device__ __forceinline__ void pack16(const float* v, ushort* dh, ushort* dl) {
    ushort hh[16], ll[16];
#pragma unroll
    for (int j = 0; j < 16; ++j) split2(v[j], hh[j], ll[j]);
    uint4 a, b;
    a.x = hh[0] | (hh[1] << 16);  a.y = hh[2] | (hh[3] << 16);
    a.z = hh[4] | (hh[5] << 16);  a.w = hh[6] | (hh[7] << 16);
    b.x = hh[8] | (hh[9] << 16);  b.y = hh[10] | (hh[11] << 16);
    b.z = hh[12] | (hh[13] << 16); b.w = hh[14] | (hh[15] << 16);
    ((uint4*)dh)[0] = a; ((uint4*)dh)[1] = b;
    a.x = ll[0] | (ll[1] << 16);  a.y = ll[2] | (ll[3] << 16);
    a.z = ll[4] | (ll[5] << 16);  a.w = ll[6] | (ll[7] << 16);
    b.x = ll[8] | (ll[9] << 16);  b.y = ll[10] | (ll[11] << 16);
    b.z = ll[12] | (ll[13] << 16); b.w = ll[14] | (ll[15] << 16);
    ((uint4*)dl)[0] = a; ((uint4*)dl)[1] = b;
}

// ---- pre-kernels ----
__global__ __launch_bounds__(256) void prep_k(const float* __restrict__ kg,
                                              ushort* __restrict__ kh,
                                              ushort* __restrict__ kl) {
    const int bh = blockIdx.y;
    const int row = blockIdx.x * 64 + (threadIdx.x >> 2);
    const int seg = threadIdx.x & 3;
    const float4* p = (const float4*)(kg + ((size_t)bh * N + row) * D + seg * 16);
    float4 f[4] = {p[0], p[1], p[2], p[3]};
    float ss = 0.f;
#pragma unroll
    for (int i = 0; i < 4; ++i)
        ss += f[i].x * f[i].x + f[i].y * f[i].y + f[i].z * f[i].z + f[i].w * f[i].w;
    ss += __shfl_xor(ss, 1, 4);
    ss += __shfl_xor(ss, 2, 4);
    const float rn = rsqrtf(ss);
    float v[16];
#pragma unroll
    for (int i = 0; i < 4; ++i) {
        v[4 * i + 0] = f[i].x * rn; v[4 * i + 1] = f[i].y * rn;
        v[4 * i + 2] = f[i].z * rn; v[4 * i + 3] = f[i].w * rn;
    }
    const size_t o = ((size_t)bh * N + row) * D + seg * 16;
    pack16(v, kh + o, kl + o);
}

__global__ __launch_bounds__(256) void prep_rpe(const float* __restrict__ rg,
                                                ushort* __restrict__ rh,
                                                ushort* __restrict__ rl) {
    const int row = blockIdx.x * 64 + (threadIdx.x >> 2);
    if (row >= 2 * N - 1) return;
    const int seg = threadIdx.x & 3;
    const float4* p = (const float4*)(rg + (size_t)row * D + seg * 16);
    float4 f[4] = {p[0], p[1], p[2], p[3]};
    float v[16];
#pragma unroll
    for (int i = 0; i < 4; ++i) {
        v[4 * i + 0] = f[i].x; v[4 * i + 1] = f[i].y;
        v[4 * i + 2] = f[i].z; v[4 * i + 3] = f[i].w;
    }
    const size_t o = (size_t)row * D + seg * 16;
    pack16(v, rh + o, rl + o);
}

__global__ __launch_bounds__(256) void prep_v(const float* __restrict__ vg,
                                              const float* __restrict__ ng,
                                              ushort* __restrict__ vh,
                                              ushort* __restrict__ vl) {
    __shared__ ushort Th[64 * 72], Tl[64 * 72];
    const int bh = blockIdx.y, c0 = blockIdx.x * 64;
    const int cl = threadIdx.x >> 2, seg = threadIdx.x & 3;
    {
        const float4* pv = (const float4*)(vg + ((size_t)bh * N + c0 + cl) * D + seg * 16);
        const float4* pn = (const float4*)(ng + ((size_t)bh * N + c0 + cl) * D + seg * 16);
#pragma unroll
        for (int i = 0; i < 4; ++i) {
            float4 fv = pv[i], fn = pn[i];
            float va[4] = {fv.x + 0.1f * fn.x, fv.y + 0.1f * fn.y,
                           fv.z + 0.1f * fn.z, fv.w + 0.1f * fn.w};
#pragma unroll
            for (int j = 0; j < 4; ++j) {
                ushort hh, ll;
                split2(va[j], hh, ll);
                const int dc = seg * 16 + i * 4 + j;
                Th[dc * 72 + cl] = hh;
                Tl[dc * 72 + cl] = ll;
            }
        }
    }
    __syncthreads();
    {
        const int dc = threadIdx.x >> 2;
        const size_t o = ((size_t)bh * D + dc) * N + c0 + seg * 16;
        uint4* sh = (uint4*)&Th[dc * 72 + seg * 16];
        uint4* sl = (uint4*)&Tl[dc * 72 + seg * 16];
        ((uint4*)(vh + o))[0] = sh[0]; ((uint4*)(vh + o))[1] = sh[1];
        ((uint4*)(vl + o))[0] = sl[0]; ((uint4*)(vl + o))[1] = sl[1];
    }
}

// ---- main ----
__device__ __forceinline__ float4v mfma6(short8 ah0, short8 ah1, short8 al0, short8 al1,
                                         const ushort* ph, const ushort* pl, float4v c) {
    short8 bh0 = *(const short8*)ph;
    short8 bh1 = *(const short8*)(ph + 32);
    short8 bl0 = *(const short8*)pl;
    short8 bl1 = *(const short8*)(pl + 32);
    c = __builtin_amdgcn_mfma_f32_16x16x32_bf16(ah0, bh0, c, 0, 0, 0);
    c = __builtin_amdgcn_mfma_f32_16x16x32_bf16(ah1, bh1, c, 0, 0, 0);
    c = __builtin_amdgcn_mfma_f32_16x16x32_bf16(ah0, bl0, c, 0, 0, 0);
    c = __builtin_amdgcn_mfma_f32_16x16x32_bf16(ah1, bl1, c, 0, 0, 0);
    c = __builtin_amdgcn_mfma_f32_16x16x32_bf16(al0, bh0, c, 0, 0, 0);
    c = __builtin_amdgcn_mfma_f32_16x16x32_bf16(al1, bh1, c, 0, 0, 0);
    return c;
}

__global__ __launch_bounds__(256, 4)
void fastmax_main(const float* __restrict__ qg,
                  const ushort* __restrict__ kh, const ushort* __restrict__ kl,
                  const ushort* __restrict__ vh, const ushort* __restrict__ vl,
                  const ushort* __restrict__ rh, const ushort* __restrict__ rl,
                  float* __restrict__ og) {
    __shared__ __align__(16) char smem[73728];
    ushort* Kh = (ushort*)smem;           // [64][LDT]
    ushort* Kl = Kh + 64 * LDT;
    ushort* Rh = Kl + 64 * LDT;           // [128][LDT]
    ushort* Rl = Rh + 128 * LDT;
    ushort* Vh = Rl + 128 * LDT;          // [64][LDT] (dc-major)
    ushort* Vl = Vh + 64 * LDT;

    const int tid  = threadIdx.x;
    const int lane = tid & 63;
    const int wv   = tid >> 6;
    const int bh   = blockIdx.y;
    const int x    = lane & 15;
    const int quad = lane >> 4;
    const int band = wv * 16;

    // per-wave scratch overlays Kh/Kl/start-of-Rh (dead between barriers B..D)
    float*  Bst = (float*)(smem + wv * 5760);   // [80][18] f32
    ushort* Sh  = (ushort*)(smem + wv * 5760);  // [16][LDT] bf16
    ushort* Sl  = Sh + 16 * LDT;

    const ushort* khb = kh + (size_t)bh * N * D;
    const ushort* klb = kl + (size_t)bh * N * D;
    const ushort* vhb = vh + (size_t)bh * D * N;
    const ushort* vlb = vl + (size_t)bh * D * N;

    for (int half = 0; half < 2; ++half) {
        const int bix = half == 0 ? (int)blockIdx.x + 8 : 7 - (int)blockIdx.x;
        const int i0  = bix * 64;

        // ---- this wave's 16 q rows -> normalized bf16x2 A-frags ----
        const float* qrow = qg + ((size_t)bh * N + i0 + band + x) * D;
        float qf[16];
        *(float4*)&qf[0]  = *(const float4*)(qrow + quad * 8);
        *(float4*)&qf[4]  = *(const float4*)(qrow + quad * 8 + 4);
        *(float4*)&qf[8]  = *(const float4*)(qrow + 32 + quad * 8);
        *(float4*)&qf[12] = *(const float4*)(qrow + 32 + quad * 8 + 4);
        float ss = 0.f;
#pragma unroll
        for (int j = 0; j < 16; ++j) ss += qf[j] * qf[j];
        ss += __shfl_xor(ss, 16);
        ss += __shfl_xor(ss, 32);
        const float rn = rsqrtf(ss);
        short8 qh0, ql0, qh1, ql1;
#pragma unroll
        for (int j = 0; j < 8; ++j) {
            ushort h, l;
            split2(qf[j] * rn, h, l);      qh0[j] = (short)h; ql0[j] = (short)l;
            split2(qf[8 + j] * rn, h, l);  qh1[j] = (short)h; ql1[j] = (short)l;
        }

        float4v oacc[4];
#pragma unroll
        for (int i = 0; i < 4; ++i) oacc[i] = (float4v){0.f, 0.f, 0.f, 0.f};
        float pden[4] = {0.f, 0.f, 0.f, 0.f};

        for (int jt = 0; jt <= bix; ++jt) {
            const int j0   = jt * 64;
            const int rel0 = i0 - j0 + N - 64;

            // ---- stage tiles: pure b128 copies (pre-split data) ----
            {
                const ushort* gKh = khb + (size_t)j0 * D;
                const ushort* gKl = klb + (size_t)j0 * D;
                const ushort* gVh = vhb + j0;   // rows dc, stride N
                const ushort* gVl = vlb + j0;
                for (int u = tid; u < 512; u += 256) {
                    const int row = u >> 3, c8 = (u & 7) * 8;
                    *(uint4*)&Kh[row * LDT + c8] = *(const uint4*)&gKh[row * D + c8];
                    *(uint4*)&Kl[row * LDT + c8] = *(const uint4*)&gKl[row * D + c8];
                    *(uint4*)&Vh[row * LDT + c8] = *(const uint4*)&gVh[(size_t)row * N + c8];
                    *(uint4*)&Vl[row * LDT + c8] = *(const uint4*)&gVl[(size_t)row * N + c8];
                }
                const ushort* gRh = rh + (size_t)rel0 * D;
                const ushort* gRl = rl + (size_t)rel0 * D;
                for (int u = tid; u < 1024; u += 256) {
                    const int row = u >> 3, c8 = (u & 7) * 8;
                    *(uint4*)&Rh[row * LDT + c8] = *(const uint4*)&gRh[row * D + c8];
                    *(uint4*)&Rl[row * LDT + c8] = *(const uint4*)&gRl[row * D + c8];
                }
            }
            __syncthreads();   // A: staging done

            // ---- QK^T ----
            float4v sacc[4];
#pragma unroll
            for (int nt = 0; nt < 4; ++nt) {
                const int off = (nt * 16 + x) * LDT + quad * 8;
                float4v c = (float4v){0.f, 0.f, 0.f, 0.f};
                sacc[nt] = mfma6(qh0, qh1, ql0, ql1, &Kh[off], &Kl[off], c);
            }
            // ---- QR: 5 w-tiles this wave gathers from (w in [band, band+80)) ----
            float4v racc[5];
#pragma unroll
            for (int t = 0; t < 5; ++t) {
                const int off = (band + t * 16 + x) * LDT + quad * 8;
                float4v c = (float4v){0.f, 0.f, 0.f, 0.f};
                racc[t] = mfma6(qh0, qh1, ql0, ql1, &Rh[off], &Rl[off], c);
            }
            __syncthreads();   // B: K/R LDS reads done; scratch region free

            // ---- intra-wave Bst transpose ----
#pragma unroll
            for (int t = 0; t < 5; ++t) {
                float* p = &Bst[(t * 16 + x) * 18 + quad * 4];
                float2 a; a.x = racc[t][0]; a.y = racc[t][1];
                float2 b; b.x = racc[t][2]; b.y = racc[t][3];
                *(float2*)p = a;
                *(float2*)(p + 2) = b;
            }
            LDS_FENCE();

            // ---- gather bias, assemble S, denom ----
            const bool diag = (jt == bix);
            float s[4][4];
#pragma unroll
            for (int nt = 0; nt < 4; ++nt) {
#pragma unroll
                for (int rr = 0; rr < 4; ++rr) {
                    const int rt = band + quad * 4 + rr;
                    const int ct = nt * 16 + x;
                    const int wl = rt - ct + 63 - band;     // [0, 78]
                    float val = sacc[nt][rr] + Bst[wl * 18 + quad * 4 + rr] + 1.0f;
                    if (diag && ct > rt) val = 0.f;
                    pden[rr] += val;
                    s[nt][rr] = val;
                }
            }
            LDS_FENCE();

            // ---- intra-wave S hi/lo store + A-frag reload ----
#pragma unroll
            for (int nt = 0; nt < 4; ++nt)
#pragma unroll
                for (int rr = 0; rr < 4; ++rr) {
                    ushort hh, ll;
                    split2(s[nt][rr], hh, ll);
                    Sh[(quad * 4 + rr) * LDT + nt * 16 + x] = hh;
                    Sl[(quad * 4 + rr) * LDT + nt * 16 + x] = ll;
                }
            LDS_FENCE();
            const short8 sh0 = *(const short8*)&Sh[x * LDT + quad * 8];
            const short8 sh1 = *(const short8*)&Sh[x * LDT + 32 + quad * 8];
            const short8 sl0 = *(const short8*)&Sl[x * LDT + quad * 8];
            const short8 sl1 = *(const short8*)&Sl[x * LDT + 32 + quad * 8];

            // ---- O += S @ V' ----
#pragma unroll
            for (int nt = 0; nt < 4; ++nt) {
                const int off = (nt * 16 + x) * LDT + quad * 8;
                oacc[nt] = mfma6(sh0, sh1, sl0, sl1, &Vh[off], &Vl[off], oacc[nt]);
            }
            __syncthreads();   // D: all reads done; next iter may restage
        }

        // ---- denominators + store ----
        float inv[4];
#pragma unroll
        for (int rr = 0; rr < 4; ++rr) {
            float d = pden[rr];
            d += __shfl_xor(d, 1, 16);
            d += __shfl_xor(d, 2, 16);
            d += __shfl_xor(d, 4, 16);
            d += __shfl_xor(d, 8, 16);
            inv[rr] = 1.0f / d;
        }
        float* outp = og + ((size_t)bh * N + i0 + band) * D;
#pragma unroll
        for (int nt = 0; nt < 4; ++nt)
#pragma unroll
            for (int rr = 0; rr < 4; ++rr)
                outp[(size_t)(quad * 4 + rr) * D + nt * 16 + x] = oacc[nt][rr] * inv[rr];
    }
}

extern "C" void kernel_launch(void* const* d_in, const int* in_sizes, int n_in,
                              void* d_out, int out_size, void* d_ws, size_t ws_size,
                              hipStream_t stream) {
    const float* q   = (const float*)d_in[0];
    const float* k   = (const float*)d_in[1];
    const float* v   = (const float*)d_in[2];
    const float* dn  = (const float*)d_in[3];
    const float* rpe = (const float*)d_in[4];
    float* out = (float*)d_out;
    char* ws = (char*)d_ws;

    ushort* kh = (ushort*)(ws + KH_OFF);
    ushort* kl = (ushort*)(ws + KL_OFF);
    ushort* vh = (ushort*)(ws + VH_OFF);
    ushort* vl = (ushort*)(ws + VL_OFF);
    ushort* rh = (ushort*)(ws + RH_OFF);
    ushort* rl = (ushort*)(ws + RL_OFF);

    prep_k  <<<dim3(N / 64, NBH), 256, 0, stream>>>(k, kh, kl);
    prep_v  <<<dim3(N / 64, NBH), 256, 0, stream>>>(v, dn, vh, vl);
    prep_rpe<<<dim3(32), 256, 0, stream>>>(rpe, rh, rl);
    fastmax_main<<<dim3(8, NBH), 256, 0, stream>>>(q, kh, kl, vh, vl, rh, rl, out);
}